// Round 15
// baseline (324.060 us; speedup 1.0000x reference)
//
#include <hip/hip_runtime.h>
#include <hip/hip_fp16.h>

#define N_NODES 50000
#define N_EDGES 800000
#define DIM 128
#define NUM_GRAPHS 128
#define STRIDE 64                      // CSR slot stride (>= max in-degree)

#define ATTR_SCALE 33554432.0f         // 2^25 fixed-point for attr sums
#define ATTR_MASK  ((1ull << 40) - 1)

typedef _Float16 f16x8 __attribute__((ext_vector_type(8)));
typedef float f32x4 __attribute__((ext_vector_type(4)));

// ===== fused CSR build + W-transpose, XCD-sliced ===========================
// NT hints on the streaming reads (dst/attr/src): they sweep 25+ MB through
// each 4 MB per-XCD L2 and were evicting partially-filled epack lines between
// their ~4 stores (R14: WRITE_SIZE 33.4 MB for ~5 MB of payload lines).

__global__ __launch_bounds__(256) void k_build(const int* __restrict__ src,
                                               const int* __restrict__ dst,
                                               const float* __restrict__ attr,
                                               const float* __restrict__ W0,
                                               const float* __restrict__ W1,
                                               unsigned long long* packed,
                                               unsigned int* __restrict__ epack,
                                               _Float16* __restrict__ Wt0,
                                               _Float16* __restrict__ Wt1,
                                               int E, int nbChunks) {
    int b = blockIdx.x;
    if (b >= nbChunks * 8) {
        int idx = (b - nbChunks * 8) * 256 + threadIdx.x;  // 32768 = 2*128*128
        int m = idx >> 14;
        int rem = idx & 16383;
        int n = rem >> 7;
        int k = rem & 127;
        const float* W = m ? W1 : W0;
        _Float16* Wt = m ? Wt1 : Wt0;
        Wt[(size_t)n * 128 + k] = (_Float16)W[(size_t)k * 128 + n];
        return;
    }
    int slice = b & 7;
    int e = (b >> 3) * 256 + threadIdx.x;
    if (e >= E) return;
    int d = __builtin_nontemporal_load(dst + e);
    if ((d & 7) != slice) return;
    float a = __builtin_nontemporal_load(attr + e);
    int s = __builtin_nontemporal_load(src + e);
    unsigned long long add =
        (1ull << 40) | (unsigned long long)(unsigned int)(a * ATTR_SCALE + 0.5f);
    unsigned long long old = atomicAdd(&packed[d], add);
    int rank = (int)(old >> 40);
    if (rank < STRIDE) {
        __half ha = __float2half_rn(a);
        unsigned short us = *reinterpret_cast<unsigned short*>(&ha);
        epack[d * STRIDE + rank] = ((unsigned int)us << 16) | (unsigned int)s;
    }
}

// ===== MFMA f16 GEMM, operand-swapped (unchanged from R14) =================

template <typename AT>
__global__ __launch_bounds__(256) void k_gemm_mfma(const AT* __restrict__ A,
                                                   const _Float16* __restrict__ Wt,
                                                   const unsigned long long* __restrict__ packed,
                                                   __half* __restrict__ H, int n) {
    int tid = threadIdx.x;
    int w = tid >> 6, lane = tid & 63;
    int n15 = lane & 15, quad = lane >> 4;
    int node = blockIdx.x * 64 + w * 16 + n15;
    int nodec = node < n ? node : n - 1;
    const AT* Arow = A + (size_t)nodec * DIM;

    f32x4 acc[8];
#pragma unroll
    for (int t = 0; t < 8; t++) acc[t] = (f32x4){0.f, 0.f, 0.f, 0.f};

#pragma unroll
    for (int c = 0; c < 4; c++) {
        f16x8 bf;
        if constexpr (__is_same(AT, float)) {
            float4 a0 = ((const float4*)Arow)[c * 8 + quad * 2];
            float4 a1 = ((const float4*)Arow)[c * 8 + quad * 2 + 1];
            bf[0] = (_Float16)a0.x; bf[1] = (_Float16)a0.y;
            bf[2] = (_Float16)a0.z; bf[3] = (_Float16)a0.w;
            bf[4] = (_Float16)a1.x; bf[5] = (_Float16)a1.y;
            bf[6] = (_Float16)a1.z; bf[7] = (_Float16)a1.w;
        } else {
            bf = *(const f16x8*)(Arow + c * 32 + quad * 8);
        }
#pragma unroll
        for (int t = 0; t < 8; t++) {
            f16x8 af = *(const f16x8*)(Wt + (size_t)(t * 16 + n15) * 128 + c * 32 + quad * 8);
            acc[t] = __builtin_amdgcn_mfma_f32_16x16x32_f16(af, bf, acc[t], 0, 0, 0);
        }
    }

    if (node < n) {
        unsigned long long pk = packed[nodec];
        float dv = rsqrtf(1.0f + (float)(pk & ATTR_MASK) * (1.0f / ATTR_SCALE));
        __half* hp = H + (size_t)node * DIM + quad * 4;
#pragma unroll
        for (int t = 0; t < 8; t++) {
            __half2 h01 = __floats2half2_rn(acc[t][0] * dv, acc[t][1] * dv);
            __half2 h23 = __floats2half2_rn(acc[t][2] * dv, acc[t][3] * dv);
            uint2 pkd;
            pkd.x = *reinterpret_cast<unsigned int*>(&h01);
            pkd.y = *reinterpret_cast<unsigned int*>(&h23);
            *(uint2*)(hp + t * 16) = pkd;
        }
    }
}

// ===== COLUMN-SLICED gather (R14) + NT epack stream ========================
// 8 lanes/node, cg = blockIdx&3 -> one 64 B line per group per instruction;
// per-XCD H' footprint 3.2 MB. epack reads are pure streaming (12.8 MB) —
// NT hint keeps them from evicting the hot H' column slice.

__device__ __forceinline__ float2 unpack_h2(unsigned int u) {
    __half2 h = *reinterpret_cast<__half2*>(&u);
    return __half22float2(h);
}

template <bool POOL>
__global__ __launch_bounds__(256) void k_gather(const __half* __restrict__ H,
                                                const unsigned long long* __restrict__ packed,
                                                const unsigned int* __restrict__ epack,
                                                const float* __restrict__ bias,
                                                const int* __restrict__ batch,
                                                __half* __restrict__ OUT,
                                                float* gsum, float* cnt, int n) {
    int cg = blockIdx.x & 3;           // column group (XCD-affine)
    int nb = blockIdx.x >> 2;          // node-block (32 nodes)
    int slot = threadIdx.x >> 3;       // node slot [0,32)
    int ln = threadIdx.x & 7;          // lane in group [0,8)
    int i = nb * 32 + slot;
    bool valid = i < n;
    int ic = valid ? i : n - 1;
    int colq = cg * 8 + ln;            // uint2 index within row [0,32)
    const uint2* H8 = (const uint2*)H;

    unsigned long long pk = packed[ic];
    int cntE = valid ? (int)(pk >> 40) : 0;
    if (cntE > STRIDE) cntE = STRIDE;
    float dv = rsqrtf(1.0f + (float)(pk & ATTR_MASK) * (1.0f / ATTR_SCALE));

    uint2 selfraw = H8[(size_t)ic * 32 + colq];
    float2 s01 = unpack_h2(selfraw.x);
    float2 s23 = unpack_h2(selfraw.y);
    float4 acc = make_float4(s01.x, s01.y, s23.x, s23.y);

    int j0 = ic * STRIDE;
    int end = j0 + cntE;

    for (int j = j0; j < end; j += 8) {
        int s[8];
        float wt[8];
#pragma unroll
        for (int k = 0; k < 8; k++) {
            int jj = j + k;
            bool v2 = jj < end;
            int jc = v2 ? jj : (end - 1);
            unsigned int pe = __builtin_nontemporal_load(epack + jc);
            s[k] = (int)(pe & 0xffffu);
            __half_raw hr;
            hr.x = (unsigned short)(pe >> 16);
            wt[k] = v2 ? __half2float(__half(hr)) : 0.f;
        }
        uint2 v[8];
#pragma unroll
        for (int k = 0; k < 8; k++) v[k] = H8[(size_t)s[k] * 32 + colq];
#pragma unroll
        for (int k = 0; k < 8; k++) {
            float2 f01 = unpack_h2(v[k].x);
            float2 f23 = unpack_h2(v[k].y);
            acc.x += wt[k] * f01.x;
            acc.y += wt[k] * f01.y;
            acc.z += wt[k] * f23.x;
            acc.w += wt[k] * f23.y;
        }
    }

    float4 bb = ((const float4*)bias)[colq];
    acc.x = fmaxf(acc.x * dv + bb.x, 0.f);
    acc.y = fmaxf(acc.y * dv + bb.y, 0.f);
    acc.z = fmaxf(acc.z * dv + bb.z, 0.f);
    acc.w = fmaxf(acc.w * dv + bb.w, 0.f);

    if constexpr (POOL) {
        __shared__ float lpool[32 * 32];  // 32 nodes x 32 feats (this cg)
        __shared__ int sg[32];
        __shared__ int meta[4];           // gA, gB, cntA, cntB
        if (ln == 0) sg[slot] = valid ? batch[ic] : -1;
        __syncthreads();
        if (threadIdx.x == 0) {
            int nv = n - nb * 32; if (nv > 32) nv = 32;
            int gA = sg[0];
            int gB = sg[nv - 1];
            int cA = 0, cB = 0;
            for (int k2 = 0; k2 < nv; k2++) {
                if (sg[k2] == gA) cA++;
                else if (sg[k2] == gB) cB++;
            }
            meta[0] = gA; meta[1] = gB; meta[2] = cA; meta[3] = cB;
        }
        __syncthreads();
        int gA = meta[0], gB = meta[1];
        int myg = valid ? sg[slot] : -2;

        bool inA = valid && (myg == gA);
        ((float4*)(lpool + slot * 32))[ln] =
            inA ? acc : make_float4(0.f, 0.f, 0.f, 0.f);
        __syncthreads();
        if (threadIdx.x < 32) {
            float ssum = 0.f;
#pragma unroll
            for (int k2 = 0; k2 < 32; k2++) ssum += lpool[k2 * 32 + threadIdx.x];
            atomicAdd(&gsum[gA * DIM + cg * 32 + threadIdx.x], ssum);
        }
        if (threadIdx.x == 0 && cg == 0) atomicAdd(&cnt[gA], (float)meta[2]);

        if (gB != gA) {
            __syncthreads();
            bool inB = valid && (myg == gB);
            ((float4*)(lpool + slot * 32))[ln] =
                inB ? acc : make_float4(0.f, 0.f, 0.f, 0.f);
            __syncthreads();
            if (threadIdx.x < 32) {
                float ssum = 0.f;
#pragma unroll
                for (int k2 = 0; k2 < 32; k2++) ssum += lpool[k2 * 32 + threadIdx.x];
                atomicAdd(&gsum[gB * DIM + cg * 32 + threadIdx.x], ssum);
            }
            if (threadIdx.x == 0 && cg == 0) atomicAdd(&cnt[gB], (float)meta[3]);
        }

        if (valid && myg != gA && myg != gB) {
            float* o = gsum + (size_t)myg * DIM + cg * 32 + ln * 4;
            atomicAdd(o + 0, acc.x);
            atomicAdd(o + 1, acc.y);
            atomicAdd(o + 2, acc.z);
            atomicAdd(o + 3, acc.w);
            if (ln == 0 && cg == 0) atomicAdd(&cnt[myg], 1.0f);
        }
    } else {
        if (valid) {
            __half2 p01 = __floats2half2_rn(acc.x, acc.y);
            __half2 p23 = __floats2half2_rn(acc.z, acc.w);
            uint2 o;
            o.x = *reinterpret_cast<unsigned int*>(&p01);
            o.y = *reinterpret_cast<unsigned int*>(&p23);
            ((uint2*)OUT)[(size_t)i * 32 + colq] = o;
        }
    }
}

// ================= classifier =================

__global__ __launch_bounds__(128) void k_classifier(const float* __restrict__ gsum,
                                                    const float* __restrict__ cnt,
                                                    const float* __restrict__ Wc1,
                                                    const float* __restrict__ bc1,
                                                    const float* __restrict__ Wc2,
                                                    const float* __restrict__ bc2,
                                                    float* __restrict__ out) {
    int g = blockIdx.x;
    int t = threadIdx.x;  // 128
    __shared__ float gv[128];
    __shared__ float hid[128];
    float inv = 1.0f / fmaxf(cnt[g], 1.0f);
    gv[t] = gsum[(size_t)g * DIM + t] * inv;
    __syncthreads();
    float acc = bc1[t];
    for (int k = 0; k < 128; k++) acc += gv[k] * Wc1[k * 128 + t];
    hid[t] = fmaxf(acc, 0.f);
    __syncthreads();
    if (t < 4) {
        float o = bc2[t];
        for (int k = 0; k < 128; k++) o += hid[k] * Wc2[k * 4 + t];
        out[g * 4 + t] = o;
    }
}

// ================= launch =================

extern "C" void kernel_launch(void* const* d_in, const int* in_sizes, int n_in,
                              void* d_out, int out_size, void* d_ws, size_t ws_size,
                              hipStream_t stream) {
    const float* x     = (const float*)d_in[0];
    const int*   ei    = (const int*)d_in[1];  // [2, E]: src then dst
    const float* attr  = (const float*)d_in[2];
    // d_in[3] edge_weight: unused by reference
    const int*   batch = (const int*)d_in[4];
    const float* W0  = (const float*)d_in[5];
    const float* b0  = (const float*)d_in[6];
    const float* W1  = (const float*)d_in[7];
    const float* b1  = (const float*)d_in[8];
    const float* Wc1 = (const float*)d_in[9];
    const float* bc1 = (const float*)d_in[10];
    const float* Wc2 = (const float*)d_in[11];
    const float* bc2 = (const float*)d_in[12];
    float* out = (float*)d_out;

    char* ws = (char*)d_ws;
    __half*             bufH16 = (__half*)(ws + 0);                  // 12,800,000
    __half*             bufA16 = (__half*)(ws + 12800000);           // 12,800,000
    unsigned int*       epack  = (unsigned int*)(ws + 25600000);     // 12,800,000
    unsigned long long* packed = (unsigned long long*)(ws + 38400000);  // 400,000
    float*              gsum   = (float*)(ws + 38800000);            //     65,536
    float*              cnt    = (float*)(ws + 38865536);            //        512
    _Float16*           Wt0    = (_Float16*)(ws + 38866048);         //     32,768
    _Float16*           Wt1    = (_Float16*)(ws + 38898816);         //     32,768

    const int* src = ei;
    const int* dst = ei + N_EDGES;

    const int NB_C = (N_EDGES + 255) / 256;            // 3125 chunks
    const int NB_G = ((N_NODES + 31) / 32) * 4;        // 1563 node-blocks x 4 cg
    const int NB_M = (N_NODES + 63) / 64;              // 782

    // zero packed+gsum+cnt (contiguous 466,048 B) without a kernel launch
    (void)hipMemsetAsync(ws + 38400000, 0, 466048, stream);

    // XCD-sliced one-pass CSR build + W transpose (NT streaming reads)
    k_build<<<NB_C * 8 + 128, 256, 0, stream>>>(src, dst, attr, W0, W1, packed,
                                                epack, Wt0, Wt1, N_EDGES, NB_C);

    // layer 1: MFMA gemm (H' = dinv*(x@W0), fp16) + column-sliced gather
    k_gemm_mfma<float><<<NB_M, 256, 0, stream>>>(x, Wt0, packed, bufH16, N_NODES);
    k_gather<false><<<NB_G, 256, 0, stream>>>(bufH16, packed, epack, b0,
                                              batch, bufA16, gsum, cnt, N_NODES);

    // layer 2: MFMA gemm (fp16 A) + column-sliced gather w/ segmented pool
    k_gemm_mfma<_Float16><<<NB_M, 256, 0, stream>>>((const _Float16*)bufA16, Wt1,
                                                    packed, bufH16, N_NODES);
    k_gather<true><<<NB_G, 256, 0, stream>>>(bufH16, packed, epack, b1,
                                             batch, nullptr, gsum, cnt, N_NODES);

    // classifier
    k_classifier<<<NUM_GRAPHS, 128, 0, stream>>>(gsum, cnt, Wc1, bc1, Wc2, bc2, out);
}

// Round 16
// 279.949 us; speedup vs baseline: 1.1576x; 1.1576x over previous
//
#include <hip/hip_runtime.h>
#include <hip/hip_fp16.h>

#define N_NODES 50000
#define N_EDGES 800000
#define DIM 128
#define NUM_GRAPHS 128
#define STRIDE 64                      // CSR slot stride (>= max in-degree)

#define ATTR_SCALE 33554432.0f         // 2^25 fixed-point for attr sums
#define ATTR_MASK  ((1ull << 40) - 1)

typedef _Float16 f16x8 __attribute__((ext_vector_type(8)));
typedef float f32x4 __attribute__((ext_vector_type(4)));

// ===== fused CSR build + W-transpose, XCD-sliced ===========================
// NT loads on streaming dst/attr/src (measured neutral, avoids L2 sweep).
// NT STORE on the epack payload: partial-line scattered stores assemble in
// the 256 MB LLC instead of thrashing 4 MB per-XCD L2 (R14: 33.4 MB HBM
// writeback for ~5 MB of dirty lines = ~7 writebacks/line).

__global__ __launch_bounds__(256) void k_build(const int* __restrict__ src,
                                               const int* __restrict__ dst,
                                               const float* __restrict__ attr,
                                               const float* __restrict__ W0,
                                               const float* __restrict__ W1,
                                               unsigned long long* packed,
                                               unsigned int* __restrict__ epack,
                                               _Float16* __restrict__ Wt0,
                                               _Float16* __restrict__ Wt1,
                                               int E, int nbChunks) {
    int b = blockIdx.x;
    if (b >= nbChunks * 8) {
        int idx = (b - nbChunks * 8) * 256 + threadIdx.x;  // 32768 = 2*128*128
        int m = idx >> 14;
        int rem = idx & 16383;
        int n = rem >> 7;
        int k = rem & 127;
        const float* W = m ? W1 : W0;
        _Float16* Wt = m ? Wt1 : Wt0;
        Wt[(size_t)n * 128 + k] = (_Float16)W[(size_t)k * 128 + n];
        return;
    }
    int slice = b & 7;
    int e = (b >> 3) * 256 + threadIdx.x;
    if (e >= E) return;
    int d = __builtin_nontemporal_load(dst + e);
    if ((d & 7) != slice) return;
    float a = __builtin_nontemporal_load(attr + e);
    int s = __builtin_nontemporal_load(src + e);
    unsigned long long add =
        (1ull << 40) | (unsigned long long)(unsigned int)(a * ATTR_SCALE + 0.5f);
    unsigned long long old = atomicAdd(&packed[d], add);
    int rank = (int)(old >> 40);
    if (rank < STRIDE) {
        __half ha = __float2half_rn(a);
        unsigned short us = *reinterpret_cast<unsigned short*>(&ha);
        unsigned int pay = ((unsigned int)us << 16) | (unsigned int)s;
        __builtin_nontemporal_store(pay, epack + d * STRIDE + rank);
    }
}

// ===== MFMA f16 GEMM, operand-swapped (unchanged from R14) =================

template <typename AT>
__global__ __launch_bounds__(256) void k_gemm_mfma(const AT* __restrict__ A,
                                                   const _Float16* __restrict__ Wt,
                                                   const unsigned long long* __restrict__ packed,
                                                   __half* __restrict__ H, int n) {
    int tid = threadIdx.x;
    int w = tid >> 6, lane = tid & 63;
    int n15 = lane & 15, quad = lane >> 4;
    int node = blockIdx.x * 64 + w * 16 + n15;
    int nodec = node < n ? node : n - 1;
    const AT* Arow = A + (size_t)nodec * DIM;

    f32x4 acc[8];
#pragma unroll
    for (int t = 0; t < 8; t++) acc[t] = (f32x4){0.f, 0.f, 0.f, 0.f};

#pragma unroll
    for (int c = 0; c < 4; c++) {
        f16x8 bf;
        if constexpr (__is_same(AT, float)) {
            float4 a0 = ((const float4*)Arow)[c * 8 + quad * 2];
            float4 a1 = ((const float4*)Arow)[c * 8 + quad * 2 + 1];
            bf[0] = (_Float16)a0.x; bf[1] = (_Float16)a0.y;
            bf[2] = (_Float16)a0.z; bf[3] = (_Float16)a0.w;
            bf[4] = (_Float16)a1.x; bf[5] = (_Float16)a1.y;
            bf[6] = (_Float16)a1.z; bf[7] = (_Float16)a1.w;
        } else {
            bf = *(const f16x8*)(Arow + c * 32 + quad * 8);
        }
#pragma unroll
        for (int t = 0; t < 8; t++) {
            f16x8 af = *(const f16x8*)(Wt + (size_t)(t * 16 + n15) * 128 + c * 32 + quad * 8);
            acc[t] = __builtin_amdgcn_mfma_f32_16x16x32_f16(af, bf, acc[t], 0, 0, 0);
        }
    }

    if (node < n) {
        unsigned long long pk = packed[nodec];
        float dv = rsqrtf(1.0f + (float)(pk & ATTR_MASK) * (1.0f / ATTR_SCALE));
        __half* hp = H + (size_t)node * DIM + quad * 4;
#pragma unroll
        for (int t = 0; t < 8; t++) {
            __half2 h01 = __floats2half2_rn(acc[t][0] * dv, acc[t][1] * dv);
            __half2 h23 = __floats2half2_rn(acc[t][2] * dv, acc[t][3] * dv);
            uint2 pkd;
            pkd.x = *reinterpret_cast<unsigned int*>(&h01);
            pkd.y = *reinterpret_cast<unsigned int*>(&h23);
            *(uint2*)(hp + t * 16) = pkd;
        }
    }
}

// ===== COLUMN-SLICED gather (exact R14 revert — NO NT on epack) ============
// 8 lanes/node, cg = blockIdx&3 -> one 64 B line per group per instruction;
// per-XCD H' footprint 3.2 MB. epack is read 4x (once per cg) — re-reads MUST
// stay L2-cached (R15's NT hint on it cost +54 MB FETCH, +24 us/dispatch).

__device__ __forceinline__ float2 unpack_h2(unsigned int u) {
    __half2 h = *reinterpret_cast<__half2*>(&u);
    return __half22float2(h);
}

template <bool POOL>
__global__ __launch_bounds__(256) void k_gather(const __half* __restrict__ H,
                                                const unsigned long long* __restrict__ packed,
                                                const unsigned int* __restrict__ epack,
                                                const float* __restrict__ bias,
                                                const int* __restrict__ batch,
                                                __half* __restrict__ OUT,
                                                float* gsum, float* cnt, int n) {
    int cg = blockIdx.x & 3;           // column group (XCD-affine)
    int nb = blockIdx.x >> 2;          // node-block (32 nodes)
    int slot = threadIdx.x >> 3;       // node slot [0,32)
    int ln = threadIdx.x & 7;          // lane in group [0,8)
    int i = nb * 32 + slot;
    bool valid = i < n;
    int ic = valid ? i : n - 1;
    int colq = cg * 8 + ln;            // uint2 index within row [0,32)
    const uint2* H8 = (const uint2*)H;

    unsigned long long pk = packed[ic];
    int cntE = valid ? (int)(pk >> 40) : 0;
    if (cntE > STRIDE) cntE = STRIDE;
    float dv = rsqrtf(1.0f + (float)(pk & ATTR_MASK) * (1.0f / ATTR_SCALE));

    uint2 selfraw = H8[(size_t)ic * 32 + colq];
    float2 s01 = unpack_h2(selfraw.x);
    float2 s23 = unpack_h2(selfraw.y);
    float4 acc = make_float4(s01.x, s01.y, s23.x, s23.y);

    int j0 = ic * STRIDE;
    int end = j0 + cntE;

    for (int j = j0; j < end; j += 8) {
        int s[8];
        float wt[8];
#pragma unroll
        for (int k = 0; k < 8; k++) {
            int jj = j + k;
            bool v2 = jj < end;
            int jc = v2 ? jj : (end - 1);
            unsigned int pe = epack[jc];
            s[k] = (int)(pe & 0xffffu);
            __half_raw hr;
            hr.x = (unsigned short)(pe >> 16);
            wt[k] = v2 ? __half2float(__half(hr)) : 0.f;
        }
        uint2 v[8];
#pragma unroll
        for (int k = 0; k < 8; k++) v[k] = H8[(size_t)s[k] * 32 + colq];
#pragma unroll
        for (int k = 0; k < 8; k++) {
            float2 f01 = unpack_h2(v[k].x);
            float2 f23 = unpack_h2(v[k].y);
            acc.x += wt[k] * f01.x;
            acc.y += wt[k] * f01.y;
            acc.z += wt[k] * f23.x;
            acc.w += wt[k] * f23.y;
        }
    }

    float4 bb = ((const float4*)bias)[colq];
    acc.x = fmaxf(acc.x * dv + bb.x, 0.f);
    acc.y = fmaxf(acc.y * dv + bb.y, 0.f);
    acc.z = fmaxf(acc.z * dv + bb.z, 0.f);
    acc.w = fmaxf(acc.w * dv + bb.w, 0.f);

    if constexpr (POOL) {
        __shared__ float lpool[32 * 32];  // 32 nodes x 32 feats (this cg)
        __shared__ int sg[32];
        __shared__ int meta[4];           // gA, gB, cntA, cntB
        if (ln == 0) sg[slot] = valid ? batch[ic] : -1;
        __syncthreads();
        if (threadIdx.x == 0) {
            int nv = n - nb * 32; if (nv > 32) nv = 32;
            int gA = sg[0];
            int gB = sg[nv - 1];
            int cA = 0, cB = 0;
            for (int k2 = 0; k2 < nv; k2++) {
                if (sg[k2] == gA) cA++;
                else if (sg[k2] == gB) cB++;
            }
            meta[0] = gA; meta[1] = gB; meta[2] = cA; meta[3] = cB;
        }
        __syncthreads();
        int gA = meta[0], gB = meta[1];
        int myg = valid ? sg[slot] : -2;

        bool inA = valid && (myg == gA);
        ((float4*)(lpool + slot * 32))[ln] =
            inA ? acc : make_float4(0.f, 0.f, 0.f, 0.f);
        __syncthreads();
        if (threadIdx.x < 32) {
            float ssum = 0.f;
#pragma unroll
            for (int k2 = 0; k2 < 32; k2++) ssum += lpool[k2 * 32 + threadIdx.x];
            atomicAdd(&gsum[gA * DIM + cg * 32 + threadIdx.x], ssum);
        }
        if (threadIdx.x == 0 && cg == 0) atomicAdd(&cnt[gA], (float)meta[2]);

        if (gB != gA) {
            __syncthreads();
            bool inB = valid && (myg == gB);
            ((float4*)(lpool + slot * 32))[ln] =
                inB ? acc : make_float4(0.f, 0.f, 0.f, 0.f);
            __syncthreads();
            if (threadIdx.x < 32) {
                float ssum = 0.f;
#pragma unroll
                for (int k2 = 0; k2 < 32; k2++) ssum += lpool[k2 * 32 + threadIdx.x];
                atomicAdd(&gsum[gB * DIM + cg * 32 + threadIdx.x], ssum);
            }
            if (threadIdx.x == 0 && cg == 0) atomicAdd(&cnt[gB], (float)meta[3]);
        }

        if (valid && myg != gA && myg != gB) {
            float* o = gsum + (size_t)myg * DIM + cg * 32 + ln * 4;
            atomicAdd(o + 0, acc.x);
            atomicAdd(o + 1, acc.y);
            atomicAdd(o + 2, acc.z);
            atomicAdd(o + 3, acc.w);
            if (ln == 0 && cg == 0) atomicAdd(&cnt[myg], 1.0f);
        }
    } else {
        if (valid) {
            __half2 p01 = __floats2half2_rn(acc.x, acc.y);
            __half2 p23 = __floats2half2_rn(acc.z, acc.w);
            uint2 o;
            o.x = *reinterpret_cast<unsigned int*>(&p01);
            o.y = *reinterpret_cast<unsigned int*>(&p23);
            ((uint2*)OUT)[(size_t)i * 32 + colq] = o;
        }
    }
}

// ================= classifier =================

__global__ __launch_bounds__(128) void k_classifier(const float* __restrict__ gsum,
                                                    const float* __restrict__ cnt,
                                                    const float* __restrict__ Wc1,
                                                    const float* __restrict__ bc1,
                                                    const float* __restrict__ Wc2,
                                                    const float* __restrict__ bc2,
                                                    float* __restrict__ out) {
    int g = blockIdx.x;
    int t = threadIdx.x;  // 128
    __shared__ float gv[128];
    __shared__ float hid[128];
    float inv = 1.0f / fmaxf(cnt[g], 1.0f);
    gv[t] = gsum[(size_t)g * DIM + t] * inv;
    __syncthreads();
    float acc = bc1[t];
    for (int k = 0; k < 128; k++) acc += gv[k] * Wc1[k * 128 + t];
    hid[t] = fmaxf(acc, 0.f);
    __syncthreads();
    if (t < 4) {
        float o = bc2[t];
        for (int k = 0; k < 128; k++) o += hid[k] * Wc2[k * 4 + t];
        out[g * 4 + t] = o;
    }
}

// ================= launch =================

extern "C" void kernel_launch(void* const* d_in, const int* in_sizes, int n_in,
                              void* d_out, int out_size, void* d_ws, size_t ws_size,
                              hipStream_t stream) {
    const float* x     = (const float*)d_in[0];
    const int*   ei    = (const int*)d_in[1];  // [2, E]: src then dst
    const float* attr  = (const float*)d_in[2];
    // d_in[3] edge_weight: unused by reference
    const int*   batch = (const int*)d_in[4];
    const float* W0  = (const float*)d_in[5];
    const float* b0  = (const float*)d_in[6];
    const float* W1  = (const float*)d_in[7];
    const float* b1  = (const float*)d_in[8];
    const float* Wc1 = (const float*)d_in[9];
    const float* bc1 = (const float*)d_in[10];
    const float* Wc2 = (const float*)d_in[11];
    const float* bc2 = (const float*)d_in[12];
    float* out = (float*)d_out;

    char* ws = (char*)d_ws;
    __half*             bufH16 = (__half*)(ws + 0);                  // 12,800,000
    __half*             bufA16 = (__half*)(ws + 12800000);           // 12,800,000
    unsigned int*       epack  = (unsigned int*)(ws + 25600000);     // 12,800,000
    unsigned long long* packed = (unsigned long long*)(ws + 38400000);  // 400,000
    float*              gsum   = (float*)(ws + 38800000);            //     65,536
    float*              cnt    = (float*)(ws + 38865536);            //        512
    _Float16*           Wt0    = (_Float16*)(ws + 38866048);         //     32,768
    _Float16*           Wt1    = (_Float16*)(ws + 38898816);         //     32,768

    const int* src = ei;
    const int* dst = ei + N_EDGES;

    const int NB_C = (N_EDGES + 255) / 256;            // 3125 chunks
    const int NB_G = ((N_NODES + 31) / 32) * 4;        // 1563 node-blocks x 4 cg
    const int NB_M = (N_NODES + 63) / 64;              // 782

    // zero packed+gsum+cnt (contiguous 466,048 B) without a kernel launch
    (void)hipMemsetAsync(ws + 38400000, 0, 466048, stream);

    // XCD-sliced one-pass CSR build + W transpose (NT loads + NT epack store)
    k_build<<<NB_C * 8 + 128, 256, 0, stream>>>(src, dst, attr, W0, W1, packed,
                                                epack, Wt0, Wt1, N_EDGES, NB_C);

    // layer 1: MFMA gemm (H' = dinv*(x@W0), fp16) + column-sliced gather
    k_gemm_mfma<float><<<NB_M, 256, 0, stream>>>(x, Wt0, packed, bufH16, N_NODES);
    k_gather<false><<<NB_G, 256, 0, stream>>>(bufH16, packed, epack, b0,
                                              batch, bufA16, gsum, cnt, N_NODES);

    // layer 2: MFMA gemm (fp16 A) + column-sliced gather w/ segmented pool
    k_gemm_mfma<_Float16><<<NB_M, 256, 0, stream>>>((const _Float16*)bufA16, Wt1,
                                                    packed, bufH16, N_NODES);
    k_gather<true><<<NB_G, 256, 0, stream>>>(bufH16, packed, epack, b1,
                                             batch, nullptr, gsum, cnt, N_NODES);

    // classifier
    k_classifier<<<NUM_GRAPHS, 128, 0, stream>>>(gsum, cnt, Wc1, bc1, Wc2, bc2, out);
}

// Round 17
// 270.009 us; speedup vs baseline: 1.2002x; 1.0368x over previous
//
#include <hip/hip_runtime.h>
#include <hip/hip_fp16.h>

#define N_NODES 50000
#define N_EDGES 800000
#define DIM 128
#define NUM_GRAPHS 128
#define STRIDE 64                      // CSR slot stride (>= max in-degree)

#define ATTR_SCALE 33554432.0f         // 2^25 fixed-point for attr sums
#define ATTR_MASK  ((1ull << 40) - 1)

typedef _Float16 f16x8 __attribute__((ext_vector_type(8)));
typedef float f32x4 __attribute__((ext_vector_type(4)));

// ===== fused CSR build + W-transpose, XCD-sliced (exact R14 state) =========
// Plain loads/stores: both NT-load (R15) and NT-store (R16) experiments
// regressed or were neutral — L2 retention is net-positive on every epack
// access path. The ~33 MB writeback is intrinsic to random partial-line
// scatter at this footprint.

__global__ __launch_bounds__(256) void k_build(const int* __restrict__ src,
                                               const int* __restrict__ dst,
                                               const float* __restrict__ attr,
                                               const float* __restrict__ W0,
                                               const float* __restrict__ W1,
                                               unsigned long long* packed,
                                               unsigned int* __restrict__ epack,
                                               _Float16* __restrict__ Wt0,
                                               _Float16* __restrict__ Wt1,
                                               int E, int nbChunks) {
    int b = blockIdx.x;
    if (b >= nbChunks * 8) {
        int idx = (b - nbChunks * 8) * 256 + threadIdx.x;  // 32768 = 2*128*128
        int m = idx >> 14;
        int rem = idx & 16383;
        int n = rem >> 7;
        int k = rem & 127;
        const float* W = m ? W1 : W0;
        _Float16* Wt = m ? Wt1 : Wt0;
        Wt[(size_t)n * 128 + k] = (_Float16)W[(size_t)k * 128 + n];
        return;
    }
    int slice = b & 7;
    int e = (b >> 3) * 256 + threadIdx.x;
    if (e >= E) return;
    int d = dst[e];
    if ((d & 7) != slice) return;
    float a = attr[e];
    unsigned long long add =
        (1ull << 40) | (unsigned long long)(unsigned int)(a * ATTR_SCALE + 0.5f);
    unsigned long long old = atomicAdd(&packed[d], add);
    int rank = (int)(old >> 40);
    if (rank < STRIDE) {
        __half ha = __float2half_rn(a);
        unsigned short us = *reinterpret_cast<unsigned short*>(&ha);
        epack[d * STRIDE + rank] = ((unsigned int)us << 16) | (unsigned int)src[e];
    }
}

// ===== MFMA f16 GEMM, operand-swapped (unchanged) ==========================

template <typename AT>
__global__ __launch_bounds__(256) void k_gemm_mfma(const AT* __restrict__ A,
                                                   const _Float16* __restrict__ Wt,
                                                   const unsigned long long* __restrict__ packed,
                                                   __half* __restrict__ H, int n) {
    int tid = threadIdx.x;
    int w = tid >> 6, lane = tid & 63;
    int n15 = lane & 15, quad = lane >> 4;
    int node = blockIdx.x * 64 + w * 16 + n15;
    int nodec = node < n ? node : n - 1;
    const AT* Arow = A + (size_t)nodec * DIM;

    f32x4 acc[8];
#pragma unroll
    for (int t = 0; t < 8; t++) acc[t] = (f32x4){0.f, 0.f, 0.f, 0.f};

#pragma unroll
    for (int c = 0; c < 4; c++) {
        f16x8 bf;
        if constexpr (__is_same(AT, float)) {
            float4 a0 = ((const float4*)Arow)[c * 8 + quad * 2];
            float4 a1 = ((const float4*)Arow)[c * 8 + quad * 2 + 1];
            bf[0] = (_Float16)a0.x; bf[1] = (_Float16)a0.y;
            bf[2] = (_Float16)a0.z; bf[3] = (_Float16)a0.w;
            bf[4] = (_Float16)a1.x; bf[5] = (_Float16)a1.y;
            bf[6] = (_Float16)a1.z; bf[7] = (_Float16)a1.w;
        } else {
            bf = *(const f16x8*)(Arow + c * 32 + quad * 8);
        }
#pragma unroll
        for (int t = 0; t < 8; t++) {
            f16x8 af = *(const f16x8*)(Wt + (size_t)(t * 16 + n15) * 128 + c * 32 + quad * 8);
            acc[t] = __builtin_amdgcn_mfma_f32_16x16x32_f16(af, bf, acc[t], 0, 0, 0);
        }
    }

    if (node < n) {
        unsigned long long pk = packed[nodec];
        float dv = rsqrtf(1.0f + (float)(pk & ATTR_MASK) * (1.0f / ATTR_SCALE));
        __half* hp = H + (size_t)node * DIM + quad * 4;
#pragma unroll
        for (int t = 0; t < 8; t++) {
            __half2 h01 = __floats2half2_rn(acc[t][0] * dv, acc[t][1] * dv);
            __half2 h23 = __floats2half2_rn(acc[t][2] * dv, acc[t][3] * dv);
            uint2 pkd;
            pkd.x = *reinterpret_cast<unsigned int*>(&h01);
            pkd.y = *reinterpret_cast<unsigned int*>(&h23);
            *(uint2*)(hp + t * 16) = pkd;
        }
    }
}

// ===== COLUMN-SLICED gather (exact R14 state) ==============================
// 8 lanes/node, cg = blockIdx&3 -> one 64 B line per group per instruction;
// per-XCD H' footprint 3.2 MB. epack read 4x (once per cg) — L2-cached.

__device__ __forceinline__ float2 unpack_h2(unsigned int u) {
    __half2 h = *reinterpret_cast<__half2*>(&u);
    return __half22float2(h);
}

template <bool POOL>
__global__ __launch_bounds__(256) void k_gather(const __half* __restrict__ H,
                                                const unsigned long long* __restrict__ packed,
                                                const unsigned int* __restrict__ epack,
                                                const float* __restrict__ bias,
                                                const int* __restrict__ batch,
                                                __half* __restrict__ OUT,
                                                float* gsum, float* cnt, int n) {
    int cg = blockIdx.x & 3;           // column group (XCD-affine)
    int nb = blockIdx.x >> 2;          // node-block (32 nodes)
    int slot = threadIdx.x >> 3;       // node slot [0,32)
    int ln = threadIdx.x & 7;          // lane in group [0,8)
    int i = nb * 32 + slot;
    bool valid = i < n;
    int ic = valid ? i : n - 1;
    int colq = cg * 8 + ln;            // uint2 index within row [0,32)
    const uint2* H8 = (const uint2*)H;

    unsigned long long pk = packed[ic];
    int cntE = valid ? (int)(pk >> 40) : 0;
    if (cntE > STRIDE) cntE = STRIDE;
    float dv = rsqrtf(1.0f + (float)(pk & ATTR_MASK) * (1.0f / ATTR_SCALE));

    uint2 selfraw = H8[(size_t)ic * 32 + colq];
    float2 s01 = unpack_h2(selfraw.x);
    float2 s23 = unpack_h2(selfraw.y);
    float4 acc = make_float4(s01.x, s01.y, s23.x, s23.y);

    int j0 = ic * STRIDE;
    int end = j0 + cntE;

    for (int j = j0; j < end; j += 8) {
        int s[8];
        float wt[8];
#pragma unroll
        for (int k = 0; k < 8; k++) {
            int jj = j + k;
            bool v2 = jj < end;
            int jc = v2 ? jj : (end - 1);
            unsigned int pe = epack[jc];
            s[k] = (int)(pe & 0xffffu);
            __half_raw hr;
            hr.x = (unsigned short)(pe >> 16);
            wt[k] = v2 ? __half2float(__half(hr)) : 0.f;
        }
        uint2 v[8];
#pragma unroll
        for (int k = 0; k < 8; k++) v[k] = H8[(size_t)s[k] * 32 + colq];
#pragma unroll
        for (int k = 0; k < 8; k++) {
            float2 f01 = unpack_h2(v[k].x);
            float2 f23 = unpack_h2(v[k].y);
            acc.x += wt[k] * f01.x;
            acc.y += wt[k] * f01.y;
            acc.z += wt[k] * f23.x;
            acc.w += wt[k] * f23.y;
        }
    }

    float4 bb = ((const float4*)bias)[colq];
    acc.x = fmaxf(acc.x * dv + bb.x, 0.f);
    acc.y = fmaxf(acc.y * dv + bb.y, 0.f);
    acc.z = fmaxf(acc.z * dv + bb.z, 0.f);
    acc.w = fmaxf(acc.w * dv + bb.w, 0.f);

    if constexpr (POOL) {
        __shared__ float lpool[32 * 32];  // 32 nodes x 32 feats (this cg)
        __shared__ int sg[32];
        __shared__ int meta[4];           // gA, gB, cntA, cntB
        if (ln == 0) sg[slot] = valid ? batch[ic] : -1;
        __syncthreads();
        if (threadIdx.x == 0) {
            int nv = n - nb * 32; if (nv > 32) nv = 32;
            int gA = sg[0];
            int gB = sg[nv - 1];
            int cA = 0, cB = 0;
            for (int k2 = 0; k2 < nv; k2++) {
                if (sg[k2] == gA) cA++;
                else if (sg[k2] == gB) cB++;
            }
            meta[0] = gA; meta[1] = gB; meta[2] = cA; meta[3] = cB;
        }
        __syncthreads();
        int gA = meta[0], gB = meta[1];
        int myg = valid ? sg[slot] : -2;

        bool inA = valid && (myg == gA);
        ((float4*)(lpool + slot * 32))[ln] =
            inA ? acc : make_float4(0.f, 0.f, 0.f, 0.f);
        __syncthreads();
        if (threadIdx.x < 32) {
            float ssum = 0.f;
#pragma unroll
            for (int k2 = 0; k2 < 32; k2++) ssum += lpool[k2 * 32 + threadIdx.x];
            atomicAdd(&gsum[gA * DIM + cg * 32 + threadIdx.x], ssum);
        }
        if (threadIdx.x == 0 && cg == 0) atomicAdd(&cnt[gA], (float)meta[2]);

        if (gB != gA) {
            __syncthreads();
            bool inB = valid && (myg == gB);
            ((float4*)(lpool + slot * 32))[ln] =
                inB ? acc : make_float4(0.f, 0.f, 0.f, 0.f);
            __syncthreads();
            if (threadIdx.x < 32) {
                float ssum = 0.f;
#pragma unroll
                for (int k2 = 0; k2 < 32; k2++) ssum += lpool[k2 * 32 + threadIdx.x];
                atomicAdd(&gsum[gB * DIM + cg * 32 + threadIdx.x], ssum);
            }
            if (threadIdx.x == 0 && cg == 0) atomicAdd(&cnt[gB], (float)meta[3]);
        }

        if (valid && myg != gA && myg != gB) {
            float* o = gsum + (size_t)myg * DIM + cg * 32 + ln * 4;
            atomicAdd(o + 0, acc.x);
            atomicAdd(o + 1, acc.y);
            atomicAdd(o + 2, acc.z);
            atomicAdd(o + 3, acc.w);
            if (ln == 0 && cg == 0) atomicAdd(&cnt[myg], 1.0f);
        }
    } else {
        if (valid) {
            __half2 p01 = __floats2half2_rn(acc.x, acc.y);
            __half2 p23 = __floats2half2_rn(acc.z, acc.w);
            uint2 o;
            o.x = *reinterpret_cast<unsigned int*>(&p01);
            o.y = *reinterpret_cast<unsigned int*>(&p23);
            ((uint2*)OUT)[(size_t)i * 32 + colq] = o;
        }
    }
}

// ================= classifier =================

__global__ __launch_bounds__(128) void k_classifier(const float* __restrict__ gsum,
                                                    const float* __restrict__ cnt,
                                                    const float* __restrict__ Wc1,
                                                    const float* __restrict__ bc1,
                                                    const float* __restrict__ Wc2,
                                                    const float* __restrict__ bc2,
                                                    float* __restrict__ out) {
    int g = blockIdx.x;
    int t = threadIdx.x;  // 128
    __shared__ float gv[128];
    __shared__ float hid[128];
    float inv = 1.0f / fmaxf(cnt[g], 1.0f);
    gv[t] = gsum[(size_t)g * DIM + t] * inv;
    __syncthreads();
    float acc = bc1[t];
    for (int k = 0; k < 128; k++) acc += gv[k] * Wc1[k * 128 + t];
    hid[t] = fmaxf(acc, 0.f);
    __syncthreads();
    if (t < 4) {
        float o = bc2[t];
        for (int k = 0; k < 128; k++) o += hid[k] * Wc2[k * 4 + t];
        out[g * 4 + t] = o;
    }
}

// ================= launch =================

extern "C" void kernel_launch(void* const* d_in, const int* in_sizes, int n_in,
                              void* d_out, int out_size, void* d_ws, size_t ws_size,
                              hipStream_t stream) {
    const float* x     = (const float*)d_in[0];
    const int*   ei    = (const int*)d_in[1];  // [2, E]: src then dst
    const float* attr  = (const float*)d_in[2];
    // d_in[3] edge_weight: unused by reference
    const int*   batch = (const int*)d_in[4];
    const float* W0  = (const float*)d_in[5];
    const float* b0  = (const float*)d_in[6];
    const float* W1  = (const float*)d_in[7];
    const float* b1  = (const float*)d_in[8];
    const float* Wc1 = (const float*)d_in[9];
    const float* bc1 = (const float*)d_in[10];
    const float* Wc2 = (const float*)d_in[11];
    const float* bc2 = (const float*)d_in[12];
    float* out = (float*)d_out;

    char* ws = (char*)d_ws;
    __half*             bufH16 = (__half*)(ws + 0);                  // 12,800,000
    __half*             bufA16 = (__half*)(ws + 12800000);           // 12,800,000
    unsigned int*       epack  = (unsigned int*)(ws + 25600000);     // 12,800,000
    unsigned long long* packed = (unsigned long long*)(ws + 38400000);  // 400,000
    float*              gsum   = (float*)(ws + 38800000);            //     65,536
    float*              cnt    = (float*)(ws + 38865536);            //        512
    _Float16*           Wt0    = (_Float16*)(ws + 38866048);         //     32,768
    _Float16*           Wt1    = (_Float16*)(ws + 38898816);         //     32,768

    const int* src = ei;
    const int* dst = ei + N_EDGES;

    const int NB_C = (N_EDGES + 255) / 256;            // 3125 chunks
    const int NB_G = ((N_NODES + 31) / 32) * 4;        // 1563 node-blocks x 4 cg
    const int NB_M = (N_NODES + 63) / 64;              // 782

    // zero packed+gsum+cnt (contiguous 466,048 B) without a kernel launch
    (void)hipMemsetAsync(ws + 38400000, 0, 466048, stream);

    // XCD-sliced one-pass CSR build + W transpose
    k_build<<<NB_C * 8 + 128, 256, 0, stream>>>(src, dst, attr, W0, W1, packed,
                                                epack, Wt0, Wt1, N_EDGES, NB_C);

    // layer 1: MFMA gemm (H' = dinv*(x@W0), fp16) + column-sliced gather
    k_gemm_mfma<float><<<NB_M, 256, 0, stream>>>(x, Wt0, packed, bufH16, N_NODES);
    k_gather<false><<<NB_G, 256, 0, stream>>>(bufH16, packed, epack, b0,
                                              batch, bufA16, gsum, cnt, N_NODES);

    // layer 2: MFMA gemm (fp16 A) + column-sliced gather w/ segmented pool
    k_gemm_mfma<_Float16><<<NB_M, 256, 0, stream>>>((const _Float16*)bufA16, Wt1,
                                                    packed, bufH16, N_NODES);
    k_gather<true><<<NB_G, 256, 0, stream>>>(bufH16, packed, epack, b1,
                                             batch, nullptr, gsum, cnt, N_NODES);

    // classifier
    k_classifier<<<NUM_GRAPHS, 128, 0, stream>>>(gsum, cnt, Wc1, bc1, Wc2, bc2, out);
}